// Round 6
// baseline (500.725 us; speedup 1.0000x reference)
//
#include <hip/hip_runtime.h>
#include <math.h>

// Contextual loss, N=1, C=256, H=W=96 -> S=9216.
// loss = log(S) - log( sum_j exp( -vcol_j ) )
//   vcol_j = min_i [ a_i * d_ij + ln S'_i ]
//   S'_i   = sum_j exp( -a_i * d_ij )
//   a_i    = 2 / (m_i + 1e-5),  m_i = min_j d_ij,  d = clip((1-cos)/2, 0)
// cos = Iv^T Tv; Iv,Tv bf16, stored transposed [S][C] (K-contiguous).
// GEMM passes are LDS-free: A fragments register-resident, B fragments
// loaded straight from global (L2-resident, 9.4 MB total) in MFMA layout.
// No __syncthreads in any K-loop. jslice = bid&7 pins each XCD to a 576 KB
// B working set (linear-bid round-robin ~ XCD id heuristic; perf-only).

typedef short v8s __attribute__((ext_vector_type(8)));
typedef float v4f __attribute__((ext_vector_type(4)));

static constexpr int Sn = 9216;
static constexpr int Cn = 256;

// ws float offsets
static constexpr size_t OFF_MEAN = 0;                      // 256 floats
static constexpr size_t OFF_MROW = 256;                    // Sn uint bits (row min d)
static constexpr size_t OFF_WROW = 256 + 9216;             // Sn floats (S'_i)
static constexpr size_t OFF_VCOL = 256 + 2 * 9216;         // Sn uint bits (col min v)
static constexpr size_t OFF_SUM  = 256 + 3 * 9216;         // 1 float
static constexpr size_t OFF_IV   = 32768;                  // Sn*Cn bf16
static constexpr size_t OFF_TV   = 32768 + (size_t)Sn * Cn / 2;

__device__ __forceinline__ unsigned bf16rne(float x) {
    unsigned u = __float_as_uint(x);
    return (u + 0x7FFFu + ((u >> 16) & 1u)) >> 16;
}

// ---------------- init ----------------
__global__ void k_init(float* ws) {
    int t = blockIdx.x * 256 + threadIdx.x;
    if (t < Sn) {
        ((unsigned*)(ws + OFF_MROW))[t] = 0x7F800000u;  // +inf
        ws[OFF_WROW + t] = 0.0f;
        ((unsigned*)(ws + OFF_VCOL))[t] = 0x7F800000u;  // +inf
    }
    if (t == 0) ws[OFF_SUM] = 0.0f;
}

// ---------------- per-channel mean of T ----------------
__global__ void k_mean(const float* __restrict__ T, float* ws) {
    __shared__ float red[256];
    int c = blockIdx.x;
    float s = 0.f;
    for (int i = threadIdx.x; i < Sn; i += 256) s += T[(size_t)c * Sn + i];
    red[threadIdx.x] = s;
    __syncthreads();
    for (int off = 128; off > 0; off >>= 1) {
        if (threadIdx.x < off) red[threadIdx.x] += red[threadIdx.x + off];
        __syncthreads();
    }
    if (threadIdx.x == 0) ws[OFF_MEAN + c] = red[0] * (1.0f / Sn);
}

// ------- center + L2 normalize along C, emit bf16 transposed [S][C] -------
__global__ __launch_bounds__(256) void k_norm(const float* __restrict__ I,
                                              const float* __restrict__ T,
                                              float* ws) {
    __shared__ float mc[256];
    __shared__ float redI[4][64], redT[4][64];
    __shared__ float riS[64], rtS[64];
    const int tid = threadIdx.x, sl = tid & 63, cq = tid >> 6;
    const int s = blockIdx.x * 64 + sl;
    mc[tid] = ws[OFF_MEAN + tid];
    __syncthreads();
    float si = 0.f, st = 0.f;
    for (int c = cq * 64; c < cq * 64 + 64; ++c) {
        float xi = I[(size_t)c * Sn + s] - mc[c];
        float xt = T[(size_t)c * Sn + s] - mc[c];
        si += xi * xi;
        st += xt * xt;
    }
    redI[cq][sl] = si;
    redT[cq][sl] = st;
    __syncthreads();
    if (tid < 64) {
        float a = redI[0][tid] + redI[1][tid] + redI[2][tid] + redI[3][tid];
        float b = redT[0][tid] + redT[1][tid] + redT[2][tid] + redT[3][tid];
        riS[tid] = 1.0f / fmaxf(sqrtf(a), 1e-12f);
        rtS[tid] = 1.0f / fmaxf(sqrtf(b), 1e-12f);
    }
    __syncthreads();
    const float ri = riS[sl], rt = rtS[sl];
    unsigned short* Iv = (unsigned short*)(ws + OFF_IV);
    unsigned short* Tv = (unsigned short*)(ws + OFF_TV);
    uint4* Ivq = (uint4*)(Iv + (size_t)s * Cn);
    uint4* Tvq = (uint4*)(Tv + (size_t)s * Cn);
    for (int c8 = cq * 8; c8 < cq * 8 + 8; ++c8) {
        unsigned iw[4], tw[4];
#pragma unroll
        for (int h = 0; h < 4; ++h) {
            int c0 = c8 * 8 + 2 * h, c1 = c0 + 1;
            float i0 = (I[(size_t)c0 * Sn + s] - mc[c0]) * ri;
            float i1 = (I[(size_t)c1 * Sn + s] - mc[c1]) * ri;
            float t0 = (T[(size_t)c0 * Sn + s] - mc[c0]) * rt;
            float t1 = (T[(size_t)c1 * Sn + s] - mc[c1]) * rt;
            iw[h] = bf16rne(i0) | (bf16rne(i1) << 16);
            tw[h] = bf16rne(t0) | (bf16rne(t1) << 16);
        }
        Ivq[c8] = make_uint4(iw[0], iw[1], iw[2], iw[3]);
        Tvq[c8] = make_uint4(tw[0], tw[1], tw[2], tw[3]);
    }
}

// Load this wave's A fragments (full K=256) straight from global.
// MFMA A-frag for window kc: lane(l15,quad) holds A[row0+l15][kc*32+quad*8..+7]
// = 16 B at v8s index row*32 + kc*4 + quad.
__device__ __forceinline__ void load_A(const v8s* __restrict__ Aq, int row0,
                                       int quad, int l15, v8s fa[4][8]) {
#pragma unroll
    for (int mt = 0; mt < 4; ++mt) {
        size_t row = row0 + mt * 16 + l15;
#pragma unroll
        for (int kc = 0; kc < 8; ++kc)
            fa[mt][kc] = Aq[row * 32 + kc * 4 + quad];
    }
}

// One 128x128 tile against register-resident fa; B from global with
// double-buffered per-K-window prefetch. acc zeroed inside.
__device__ __forceinline__ void tile_mma_g(const v8s* __restrict__ Bq,
                                           size_t j0, int wn, int quad, int l15,
                                           const v8s fa[4][8], v4f acc[4][4]) {
#pragma unroll
    for (int mt = 0; mt < 4; ++mt)
#pragma unroll
        for (int nt = 0; nt < 4; ++nt)
#pragma unroll
            for (int r = 0; r < 4; ++r) acc[mt][nt][r] = 0.f;
    size_t brow[4];
    v8s fb[2][4];
#pragma unroll
    for (int nt = 0; nt < 4; ++nt) {
        brow[nt] = (j0 + wn * 64 + nt * 16 + l15) * 32 + quad;
        fb[0][nt] = Bq[brow[nt]];
    }
#pragma unroll
    for (int kc = 0; kc < 8; ++kc) {
        int cur = kc & 1, nxt = cur ^ 1;
        if (kc < 7) {
#pragma unroll
            for (int nt = 0; nt < 4; ++nt)
                fb[nxt][nt] = Bq[brow[nt] + (size_t)(kc + 1) * 4];
        }
#pragma unroll
        for (int nt = 0; nt < 4; ++nt)
#pragma unroll
            for (int mt = 0; mt < 4; ++mt)
                acc[mt][nt] = __builtin_amdgcn_mfma_f32_16x16x32_bf16(
                    fa[mt][kc], fb[cur][nt], acc[mt][nt], 0, 0, 0);
    }
}

// ---------------- pass 1: m_i = min_j d_ij ----------------
__global__ __launch_bounds__(256, 2) void k_rowmin(float* ws) {
    const v8s* Ivq = (const v8s*)(ws + OFF_IV);
    const v8s* Tvq = (const v8s*)(ws + OFF_TV);
    const int bid = blockIdx.x, jsl = bid & 7, rb = bid >> 3;
    const int tid = threadIdx.x, lane = tid & 63, wave = tid >> 6;
    const int wm = wave >> 1, wn = wave & 1, quad = (lane >> 4) & 3, l15 = lane & 15;
    const int i0 = rb * 128;
    v8s fa[4][8];
    load_A(Ivq, i0 + wm * 64, quad, l15, fa);
    float mv[4][4];
#pragma unroll
    for (int mt = 0; mt < 4; ++mt)
#pragma unroll
        for (int r = 0; r < 4; ++r) mv[mt][r] = INFINITY;
    for (int t = 0; t < 9; ++t) {
        size_t j0 = (size_t)jsl * 1152 + t * 128;
        v4f acc[4][4];
        tile_mma_g(Tvq, j0, wn, quad, l15, fa, acc);
#pragma unroll
        for (int mt = 0; mt < 4; ++mt)
#pragma unroll
            for (int nt = 0; nt < 4; ++nt)
#pragma unroll
                for (int r = 0; r < 4; ++r) {
                    float d = fmaxf(0.5f - 0.5f * acc[mt][nt][r], 0.0f);
                    mv[mt][r] = fminf(mv[mt][r], d);
                }
    }
#pragma unroll
    for (int mt = 0; mt < 4; ++mt)
#pragma unroll
        for (int r = 0; r < 4; ++r) {
            float m = mv[mt][r];
            for (int off = 1; off < 16; off <<= 1)
                m = fminf(m, __shfl_xor(m, off, 64));
            if (l15 == 0)
                atomicMin((unsigned*)(ws + OFF_MROW) + i0 + wm * 64 + mt * 16 + quad * 4 + r,
                          __float_as_uint(m));
        }
}

// ---------------- pass 2: S'_i = sum_j exp(-a_i * d_ij) ----------------
__global__ __launch_bounds__(256, 2) void k_rowsum(float* ws) {
    const v8s* Ivq = (const v8s*)(ws + OFF_IV);
    const v8s* Tvq = (const v8s*)(ws + OFF_TV);
    const int bid = blockIdx.x, jsl = bid & 7, rb = bid >> 3;
    const int tid = threadIdx.x, lane = tid & 63, wave = tid >> 6;
    const int wm = wave >> 1, wn = wave & 1, quad = (lane >> 4) & 3, l15 = lane & 15;
    const int i0 = rb * 128;
    v8s fa[4][8];
    load_A(Ivq, i0 + wm * 64, quad, l15, fa);
    float c1[4][4], run[4][4];
#pragma unroll
    for (int mt = 0; mt < 4; ++mt)
#pragma unroll
        for (int r = 0; r < 4; ++r) {
            int i = i0 + wm * 64 + mt * 16 + quad * 4 + r;
            float mm = __uint_as_float(((unsigned*)(ws + OFF_MROW))[i]);
            c1[mt][r] = -1.4426950408889634f * 2.0f / (mm + 1e-5f);  // -a*log2e
            run[mt][r] = 0.f;
        }
    for (int t = 0; t < 9; ++t) {
        size_t j0 = (size_t)jsl * 1152 + t * 128;
        v4f acc[4][4];
        tile_mma_g(Tvq, j0, wn, quad, l15, fa, acc);
#pragma unroll
        for (int mt = 0; mt < 4; ++mt)
#pragma unroll
            for (int nt = 0; nt < 4; ++nt)
#pragma unroll
                for (int r = 0; r < 4; ++r) {
                    float d = fmaxf(0.5f - 0.5f * acc[mt][nt][r], 0.0f);
                    run[mt][r] += __builtin_amdgcn_exp2f(c1[mt][r] * d);
                }
    }
#pragma unroll
    for (int mt = 0; mt < 4; ++mt)
#pragma unroll
        for (int r = 0; r < 4; ++r) {
            float s = run[mt][r];
            for (int off = 1; off < 16; off <<= 1)
                s += __shfl_xor(s, off, 64);
            if (l15 == 0)
                atomicAdd(ws + OFF_WROW + i0 + wm * 64 + mt * 16 + quad * 4 + r, s);
        }
}

// ------- pass 3: vcol_j = min_i [ a_i * d_ij + ln S'_i ] -------------
// Tile rows = j (A from Tv), tile cols = i (B from Iv); i-range is the
// XCD-pinned slice.
__global__ __launch_bounds__(256, 2) void k_colmin(float* ws) {
    const v8s* Ivq = (const v8s*)(ws + OFF_IV);
    const v8s* Tvq = (const v8s*)(ws + OFF_TV);
    const int bid = blockIdx.x, isl = bid & 7, rb = bid >> 3;
    const int tid = threadIdx.x, lane = tid & 63, wave = tid >> 6;
    const int wm = wave >> 1, wn = wave & 1, quad = (lane >> 4) & 3, l15 = lane & 15;
    const int j0 = rb * 128;
    v8s fa[4][8];
    load_A(Tvq, j0 + wm * 64, quad, l15, fa);
    float vmin[4][4];
#pragma unroll
    for (int mt = 0; mt < 4; ++mt)
#pragma unroll
        for (int r = 0; r < 4; ++r) vmin[mt][r] = INFINITY;
    for (int t = 0; t < 9; ++t) {
        size_t i0 = (size_t)isl * 1152 + t * 128;
        v4f acc[4][4];
        tile_mma_g(Ivq, i0, wn, quad, l15, fa, acc);  // acc = cos[j][i]
#pragma unroll
        for (int nt = 0; nt < 4; ++nt) {
            int i = (int)i0 + wn * 64 + nt * 16 + l15;
            float mm = __uint_as_float(((unsigned*)(ws + OFF_MROW))[i]);
            float a = 2.0f / (mm + 1e-5f);
            float lw = __builtin_amdgcn_logf(ws[OFF_WROW + i]) * 0.6931471805599453f;
#pragma unroll
            for (int mt = 0; mt < 4; ++mt)
#pragma unroll
                for (int r = 0; r < 4; ++r) {
                    float d = fmaxf(0.5f - 0.5f * acc[mt][nt][r], 0.0f);
                    vmin[mt][r] = fminf(vmin[mt][r], a * d + lw);
                }
        }
    }
#pragma unroll
    for (int mt = 0; mt < 4; ++mt)
#pragma unroll
        for (int r = 0; r < 4; ++r) {
            float v = vmin[mt][r];
            for (int off = 1; off < 16; off <<= 1)
                v = fminf(v, __shfl_xor(v, off, 64));
            if (l15 == 0)
                atomicMin((unsigned*)(ws + OFF_VCOL) + j0 + wm * 64 + mt * 16 + quad * 4 + r,
                          __float_as_uint(v));
        }
}

// ---------------- final: parallel sum then scalar write ----------------
__global__ void k_fsum(float* ws) {
    __shared__ float red[256];
    int j0 = blockIdx.x * 256 + threadIdx.x;
    float s = expf(-__uint_as_float(((const unsigned*)(ws + OFF_VCOL))[j0]));
    red[threadIdx.x] = s;
    __syncthreads();
    for (int off = 128; off > 0; off >>= 1) {
        if (threadIdx.x < off) red[threadIdx.x] += red[threadIdx.x + off];
        __syncthreads();
    }
    if (threadIdx.x == 0) atomicAdd(ws + OFF_SUM, red[0]);
}

__global__ void k_fwrite(const float* __restrict__ ws, float* __restrict__ out) {
    out[0] = logf((float)Sn) - logf(ws[OFF_SUM]);
}

extern "C" void kernel_launch(void* const* d_in, const int* in_sizes, int n_in,
                              void* d_out, int out_size, void* d_ws, size_t ws_size,
                              hipStream_t stream) {
    const float* I = (const float*)d_in[0];
    const float* T = (const float*)d_in[1];
    float* ws = (float*)d_ws;
    float* out = (float*)d_out;

    k_init<<<36, 256, 0, stream>>>(ws);
    k_mean<<<Cn, 256, 0, stream>>>(T, ws);
    k_norm<<<144, 256, 0, stream>>>(I, T, ws);
    k_rowmin<<<576, 256, 0, stream>>>(ws);
    k_rowsum<<<576, 256, 0, stream>>>(ws);
    k_colmin<<<576, 256, 0, stream>>>(ws);
    k_fsum<<<36, 256, 0, stream>>>(ws);
    k_fwrite<<<1, 1, 0, stream>>>(ws, out);
}

// Round 7
// 474.381 us; speedup vs baseline: 1.0555x; 1.0555x over previous
//
#include <hip/hip_runtime.h>
#include <math.h>

// Contextual loss, N=1, C=256, H=W=96 -> S=9216.
// loss = log(S) - log( sum_j exp( -vcol_j ) )
//   vcol_j = min_i [ a_i * d_ij + ln S'_i ]
//   S'_i   = sum_j exp( -a_i * d_ij )
//   a_i    = 2 / (m_i + 1e-5),  m_i = min_j d_ij,  d = clip((1-cos)/2, 0)
// cos = Iv^T Tv; Iv,Tv bf16, stored transposed [S][C] (K-contiguous, NT GEMM).
// GEMM passes: A fragments register-resident; B staged in 32 KB half-K
// slices via global_load_lds with DOUBLE-BUFFERED prefetch (prefetch issued
// right after each barrier so the next barrier's vmcnt(0) drain is absorbed
// by the compute phase). 16-chunk XOR swizzle -> 2-way (free) LDS reads.

typedef short v8s __attribute__((ext_vector_type(8)));
typedef float v4f __attribute__((ext_vector_type(4)));

static constexpr int Sn = 9216;
static constexpr int Cn = 256;

// ws float offsets
static constexpr size_t OFF_MEAN = 0;                      // 256 floats
static constexpr size_t OFF_MROW = 256;                    // Sn uint bits (row min d)
static constexpr size_t OFF_WROW = 256 + 9216;             // Sn floats (S'_i)
static constexpr size_t OFF_VCOL = 256 + 2 * 9216;         // Sn uint bits (col min v)
static constexpr size_t OFF_SUM  = 256 + 3 * 9216;         // 1 float
static constexpr size_t OFF_IV   = 32768;                  // Sn*Cn bf16
static constexpr size_t OFF_TV   = 32768 + (size_t)Sn * Cn / 2;

__device__ __forceinline__ unsigned bf16rne(float x) {
    unsigned u = __float_as_uint(x);
    return (u + 0x7FFFu + ((u >> 16) & 1u)) >> 16;
}

__device__ __forceinline__ void gload_lds16(const void* g, void* l) {
    __builtin_amdgcn_global_load_lds(
        (const __attribute__((address_space(1))) unsigned*)g,
        (__attribute__((address_space(3))) unsigned*)l, 16, 0, 0);
}

// ---------------- init ----------------
__global__ void k_init(float* ws) {
    int t = blockIdx.x * 256 + threadIdx.x;
    if (t < Sn) {
        ((unsigned*)(ws + OFF_MROW))[t] = 0x7F800000u;  // +inf
        ws[OFF_WROW + t] = 0.0f;
        ((unsigned*)(ws + OFF_VCOL))[t] = 0x7F800000u;  // +inf
    }
    if (t == 0) ws[OFF_SUM] = 0.0f;
}

// ---------------- per-channel mean of T ----------------
__global__ void k_mean(const float* __restrict__ T, float* ws) {
    __shared__ float red[256];
    int c = blockIdx.x;
    float s = 0.f;
    for (int i = threadIdx.x; i < Sn; i += 256) s += T[(size_t)c * Sn + i];
    red[threadIdx.x] = s;
    __syncthreads();
    for (int off = 128; off > 0; off >>= 1) {
        if (threadIdx.x < off) red[threadIdx.x] += red[threadIdx.x + off];
        __syncthreads();
    }
    if (threadIdx.x == 0) ws[OFF_MEAN + c] = red[0] * (1.0f / Sn);
}

// ------- center + L2 normalize along C, emit bf16 transposed [S][C] -------
__global__ __launch_bounds__(256) void k_norm(const float* __restrict__ I,
                                              const float* __restrict__ T,
                                              float* ws) {
    __shared__ float mc[256];
    __shared__ float redI[4][64], redT[4][64];
    __shared__ float riS[64], rtS[64];
    const int tid = threadIdx.x, sl = tid & 63, cq = tid >> 6;
    const int s = blockIdx.x * 64 + sl;
    mc[tid] = ws[OFF_MEAN + tid];
    __syncthreads();
    float si = 0.f, st = 0.f;
    for (int c = cq * 64; c < cq * 64 + 64; ++c) {
        float xi = I[(size_t)c * Sn + s] - mc[c];
        float xt = T[(size_t)c * Sn + s] - mc[c];
        si += xi * xi;
        st += xt * xt;
    }
    redI[cq][sl] = si;
    redT[cq][sl] = st;
    __syncthreads();
    if (tid < 64) {
        float a = redI[0][tid] + redI[1][tid] + redI[2][tid] + redI[3][tid];
        float b = redT[0][tid] + redT[1][tid] + redT[2][tid] + redT[3][tid];
        riS[tid] = 1.0f / fmaxf(sqrtf(a), 1e-12f);
        rtS[tid] = 1.0f / fmaxf(sqrtf(b), 1e-12f);
    }
    __syncthreads();
    const float ri = riS[sl], rt = rtS[sl];
    unsigned short* Iv = (unsigned short*)(ws + OFF_IV);
    unsigned short* Tv = (unsigned short*)(ws + OFF_TV);
    uint4* Ivq = (uint4*)(Iv + (size_t)s * Cn);
    uint4* Tvq = (uint4*)(Tv + (size_t)s * Cn);
    for (int c8 = cq * 8; c8 < cq * 8 + 8; ++c8) {
        unsigned iw[4], tw[4];
#pragma unroll
        for (int h = 0; h < 4; ++h) {
            int c0 = c8 * 8 + 2 * h, c1 = c0 + 1;
            float i0 = (I[(size_t)c0 * Sn + s] - mc[c0]) * ri;
            float i1 = (I[(size_t)c1 * Sn + s] - mc[c1]) * ri;
            float t0 = (T[(size_t)c0 * Sn + s] - mc[c0]) * rt;
            float t1 = (T[(size_t)c1 * Sn + s] - mc[c1]) * rt;
            iw[h] = bf16rne(i0) | (bf16rne(i1) << 16);
            tw[h] = bf16rne(t0) | (bf16rne(t1) << 16);
        }
        Ivq[c8] = make_uint4(iw[0], iw[1], iw[2], iw[3]);
        Tvq[c8] = make_uint4(tw[0], tw[1], tw[2], tw[3]);
    }
}

// Stage one half-K slice (128 rows x 256 B) into a 32 KB LDS buffer.
// LDS: [row][16 phys chunks of 16B], phys p = logical c ^ (row & 15).
// Swizzle on global gather side (LDS dest = uniform base + lane*16).
__device__ __forceinline__ void stage_half(const char* Gb, int h, char* dst,
                                           int tid) {
    const int lane = tid & 63, wave = tid >> 6;
    const int rs = lane >> 4;   // row within 4-row group
    const int p = lane & 15;    // phys chunk
#pragma unroll
    for (int inst = 0; inst < 8; ++inst) {
        int R = wave * 32 + inst * 4;
        int row = R + rs;
        int c = p ^ (row & 15);
        gload_lds16(Gb + (size_t)row * 512 + h * 256 + c * 16,
                    dst + (size_t)R * 256);
    }
}

// Read this wave's A fragments for one K-half from the staged buffer.
// h must be a compile-time constant at the call site (fa stays in VGPRs).
__device__ __forceinline__ void read_fa(const char* buf, int h, int wm,
                                        int quad, int l15, v8s fa[4][8]) {
#pragma unroll
    for (int l = 0; l < 4; ++l) {
#pragma unroll
        for (int mt = 0; mt < 4; ++mt) {
            int row = wm * 64 + mt * 16 + l15;
            int p = (l * 4 + quad) ^ (row & 15);
            fa[mt][h * 4 + l] = *(const v8s*)(buf + row * 256 + p * 16);
        }
    }
}

// MFMA one K-half of a 128x128 tile from the staged buffer.
__device__ __forceinline__ void compute_half(const char* buf, int h, int wn,
                                             int quad, int l15,
                                             const v8s fa[4][8], v4f acc[4][4]) {
#pragma unroll
    for (int l = 0; l < 4; ++l) {
#pragma unroll
        for (int nt = 0; nt < 4; ++nt) {
            int row = wn * 64 + nt * 16 + l15;
            int p = (l * 4 + quad) ^ (row & 15);
            v8s fb = *(const v8s*)(buf + row * 256 + p * 16);
#pragma unroll
            for (int mt = 0; mt < 4; ++mt)
                acc[mt][nt] = __builtin_amdgcn_mfma_f32_16x16x32_bf16(
                    fa[mt][h * 4 + l], fb, acc[mt][nt], 0, 0, 0);
        }
    }
}

#define GEMM_PIPELINE_PROLOGUE(Ab, Bb_t0)                                      \
    stage_half(Ab, 0, lds0, tid);                                              \
    __syncthreads();                                                           \
    stage_half(Ab, 1, lds1, tid);                                              \
    read_fa(lds0, 0, wm, quad, l15, fa);                                       \
    __syncthreads();                                                           \
    stage_half(Bb_t0, 0, lds0, tid);                                           \
    read_fa(lds1, 1, wm, quad, l15, fa);                                       \
    __syncthreads();

// ---------------- pass 1: m_i = min_j d_ij ----------------
__global__ __launch_bounds__(256, 2) void k_rowmin(float* ws) {
    __shared__ __align__(16) char ldsbuf[2][32768];
    char* lds0 = ldsbuf[0];
    char* lds1 = ldsbuf[1];
    const char* Ivb = (const char*)(ws + OFF_IV);
    const char* Tvb = (const char*)(ws + OFF_TV);
    const int tid = threadIdx.x, lane = tid & 63, wave = tid >> 6;
    const int wm = wave >> 1, wn = wave & 1, quad = (lane >> 4) & 3, l15 = lane & 15;
    const int i0 = blockIdx.x * 128;
    v8s fa[4][8];
    const char* Ab = Ivb + (size_t)i0 * 512;
    const char* Bt0 = Tvb + (size_t)(blockIdx.y * 9) * 128 * 512;
    GEMM_PIPELINE_PROLOGUE(Ab, Bt0)
    float mv[4][4];
    v4f acc[4][4];
#pragma unroll
    for (int mt = 0; mt < 4; ++mt)
#pragma unroll
        for (int r = 0; r < 4; ++r) {
            mv[mt][r] = INFINITY;
#pragma unroll
            for (int nt = 0; nt < 4; ++nt) acc[mt][nt][r] = 0.f;
        }
    for (int t = 0; t < 9; ++t) {
        const char* Bb = Tvb + (size_t)((blockIdx.y * 9 + t) * 128) * 512;
        // half 0 resident in lds0; prefetch half 1
        stage_half(Bb, 1, lds1, tid);
        compute_half(lds0, 0, wn, quad, l15, fa, acc);
        __syncthreads();
        // half 1 resident in lds1; prefetch next tile's half 0
        if (t < 8) {
            const char* Bn = Tvb + (size_t)((blockIdx.y * 9 + t + 1) * 128) * 512;
            stage_half(Bn, 0, lds0, tid);
        }
        compute_half(lds1, 1, wn, quad, l15, fa, acc);
        __syncthreads();
        // tile epilogue
#pragma unroll
        for (int mt = 0; mt < 4; ++mt)
#pragma unroll
            for (int nt = 0; nt < 4; ++nt)
#pragma unroll
                for (int r = 0; r < 4; ++r) {
                    float d = fmaxf(0.5f - 0.5f * acc[mt][nt][r], 0.0f);
                    mv[mt][r] = fminf(mv[mt][r], d);
                    acc[mt][nt][r] = 0.f;
                }
    }
#pragma unroll
    for (int mt = 0; mt < 4; ++mt)
#pragma unroll
        for (int r = 0; r < 4; ++r) {
            float m = mv[mt][r];
            for (int off = 1; off < 16; off <<= 1)
                m = fminf(m, __shfl_xor(m, off, 64));
            if (l15 == 0)
                atomicMin((unsigned*)(ws + OFF_MROW) + i0 + wm * 64 + mt * 16 + quad * 4 + r,
                          __float_as_uint(m));
        }
}

// ---------------- pass 2: S'_i = sum_j exp(-a_i * d_ij) ----------------
__global__ __launch_bounds__(256, 2) void k_rowsum(float* ws) {
    __shared__ __align__(16) char ldsbuf[2][32768];
    char* lds0 = ldsbuf[0];
    char* lds1 = ldsbuf[1];
    const char* Ivb = (const char*)(ws + OFF_IV);
    const char* Tvb = (const char*)(ws + OFF_TV);
    const int tid = threadIdx.x, lane = tid & 63, wave = tid >> 6;
    const int wm = wave >> 1, wn = wave & 1, quad = (lane >> 4) & 3, l15 = lane & 15;
    const int i0 = blockIdx.x * 128;
    v8s fa[4][8];
    const char* Ab = Ivb + (size_t)i0 * 512;
    const char* Bt0 = Tvb + (size_t)(blockIdx.y * 9) * 128 * 512;
    GEMM_PIPELINE_PROLOGUE(Ab, Bt0)
    float c1[4][4], run[4][4];
    v4f acc[4][4];
#pragma unroll
    for (int mt = 0; mt < 4; ++mt)
#pragma unroll
        for (int r = 0; r < 4; ++r) {
            int i = i0 + wm * 64 + mt * 16 + quad * 4 + r;
            float mm = __uint_as_float(((unsigned*)(ws + OFF_MROW))[i]);
            c1[mt][r] = -1.4426950408889634f * 2.0f / (mm + 1e-5f);  // -a*log2e
            run[mt][r] = 0.f;
#pragma unroll
            for (int nt = 0; nt < 4; ++nt) acc[mt][nt][r] = 0.f;
        }
    for (int t = 0; t < 9; ++t) {
        const char* Bb = Tvb + (size_t)((blockIdx.y * 9 + t) * 128) * 512;
        stage_half(Bb, 1, lds1, tid);
        compute_half(lds0, 0, wn, quad, l15, fa, acc);
        __syncthreads();
        if (t < 8) {
            const char* Bn = Tvb + (size_t)((blockIdx.y * 9 + t + 1) * 128) * 512;
            stage_half(Bn, 0, lds0, tid);
        }
        compute_half(lds1, 1, wn, quad, l15, fa, acc);
        __syncthreads();
#pragma unroll
        for (int mt = 0; mt < 4; ++mt)
#pragma unroll
            for (int nt = 0; nt < 4; ++nt)
#pragma unroll
                for (int r = 0; r < 4; ++r) {
                    float d = fmaxf(0.5f - 0.5f * acc[mt][nt][r], 0.0f);
                    run[mt][r] += __builtin_amdgcn_exp2f(c1[mt][r] * d);
                    acc[mt][nt][r] = 0.f;
                }
    }
#pragma unroll
    for (int mt = 0; mt < 4; ++mt)
#pragma unroll
        for (int r = 0; r < 4; ++r) {
            float s = run[mt][r];
            for (int off = 1; off < 16; off <<= 1)
                s += __shfl_xor(s, off, 64);
            if (l15 == 0)
                atomicAdd(ws + OFF_WROW + i0 + wm * 64 + mt * 16 + quad * 4 + r, s);
        }
}

// ------- pass 3: vcol_j = min_i [ a_i * d_ij + ln S'_i ] -------------
// Tile rows = j (A from Tv), tile cols = i (B from Iv).
__global__ __launch_bounds__(256, 2) void k_colmin(float* ws) {
    __shared__ __align__(16) char ldsbuf[2][32768];
    char* lds0 = ldsbuf[0];
    char* lds1 = ldsbuf[1];
    const char* Ivb = (const char*)(ws + OFF_IV);
    const char* Tvb = (const char*)(ws + OFF_TV);
    const int tid = threadIdx.x, lane = tid & 63, wave = tid >> 6;
    const int wm = wave >> 1, wn = wave & 1, quad = (lane >> 4) & 3, l15 = lane & 15;
    const int j0 = blockIdx.x * 128;
    v8s fa[4][8];
    const char* Ab = Tvb + (size_t)j0 * 512;
    const char* Bt0 = Ivb + (size_t)(blockIdx.y * 9) * 128 * 512;
    GEMM_PIPELINE_PROLOGUE(Ab, Bt0)
    float vmin[4][4];
    v4f acc[4][4];
#pragma unroll
    for (int mt = 0; mt < 4; ++mt)
#pragma unroll
        for (int r = 0; r < 4; ++r) {
            vmin[mt][r] = INFINITY;
#pragma unroll
            for (int nt = 0; nt < 4; ++nt) acc[mt][nt][r] = 0.f;
        }
    for (int t = 0; t < 9; ++t) {
        int ib = (blockIdx.y * 9 + t) * 128;
        const char* Bb = Ivb + (size_t)ib * 512;
        stage_half(Bb, 1, lds1, tid);
        compute_half(lds0, 0, wn, quad, l15, fa, acc);
        __syncthreads();
        if (t < 8) {
            const char* Bn = Ivb + (size_t)((blockIdx.y * 9 + t + 1) * 128) * 512;
            stage_half(Bn, 0, lds0, tid);
        }
        compute_half(lds1, 1, wn, quad, l15, fa, acc);
        __syncthreads();
        // tile epilogue: acc = cos[j][i] for i-block ib
#pragma unroll
        for (int nt = 0; nt < 4; ++nt) {
            int i = ib + wn * 64 + nt * 16 + l15;
            float mm = __uint_as_float(((unsigned*)(ws + OFF_MROW))[i]);
            float a = 2.0f / (mm + 1e-5f);
            float lw = __builtin_amdgcn_logf(ws[OFF_WROW + i]) * 0.6931471805599453f;
#pragma unroll
            for (int mt = 0; mt < 4; ++mt)
#pragma unroll
                for (int r = 0; r < 4; ++r) {
                    float d = fmaxf(0.5f - 0.5f * acc[mt][nt][r], 0.0f);
                    vmin[mt][r] = fminf(vmin[mt][r], a * d + lw);
                    acc[mt][nt][r] = 0.f;
                }
        }
    }
#pragma unroll
    for (int mt = 0; mt < 4; ++mt)
#pragma unroll
        for (int r = 0; r < 4; ++r) {
            float v = vmin[mt][r];
            for (int off = 1; off < 16; off <<= 1)
                v = fminf(v, __shfl_xor(v, off, 64));
            if (l15 == 0)
                atomicMin((unsigned*)(ws + OFF_VCOL) + j0 + wm * 64 + mt * 16 + quad * 4 + r,
                          __float_as_uint(v));
        }
}

// ---------------- final: parallel sum then scalar write ----------------
__global__ void k_fsum(float* ws) {
    __shared__ float red[256];
    int j0 = blockIdx.x * 256 + threadIdx.x;
    float s = expf(-__uint_as_float(((const unsigned*)(ws + OFF_VCOL))[j0]));
    red[threadIdx.x] = s;
    __syncthreads();
    for (int off = 128; off > 0; off >>= 1) {
        if (threadIdx.x < off) red[threadIdx.x] += red[threadIdx.x + off];
        __syncthreads();
    }
    if (threadIdx.x == 0) atomicAdd(ws + OFF_SUM, red[0]);
}

__global__ void k_fwrite(const float* __restrict__ ws, float* __restrict__ out) {
    out[0] = logf((float)Sn) - logf(ws[OFF_SUM]);
}

extern "C" void kernel_launch(void* const* d_in, const int* in_sizes, int n_in,
                              void* d_out, int out_size, void* d_ws, size_t ws_size,
                              hipStream_t stream) {
    const float* I = (const float*)d_in[0];
    const float* T = (const float*)d_in[1];
    float* ws = (float*)d_ws;
    float* out = (float*)d_out;

    k_init<<<36, 256, 0, stream>>>(ws);
    k_mean<<<Cn, 256, 0, stream>>>(T, ws);
    k_norm<<<144, 256, 0, stream>>>(I, T, ws);
    k_rowmin<<<dim3(72, 8), 256, 0, stream>>>(ws);
    k_rowsum<<<dim3(72, 8), 256, 0, stream>>>(ws);
    k_colmin<<<dim3(72, 8), 256, 0, stream>>>(ws);
    k_fsum<<<36, 256, 0, stream>>>(ws);
    k_fwrite<<<1, 1, 0, stream>>>(ws, out);
}

// Round 8
// 316.208 us; speedup vs baseline: 1.5835x; 1.5002x over previous
//
#include <hip/hip_runtime.h>
#include <math.h>

// Contextual loss, N=1, C=256, H=W=96 -> S=9216.
// loss = log(S) - log( sum_j exp( -vcol_j ) )
//   vcol_j = min_i [ a_i * d_ij + ln S'_i ]
//   S'_i   = sum_j exp( -a_i * d_ij )
//   a_i    = 2 / (m_i + 1e-5),  m_i = min_j d_ij,  d = clip((1-cos)/2, 0)
// cos = Iv^T Tv; Iv,Tv bf16, stored transposed [S][C] (K-contiguous, NT GEMM).
// GEMM passes: round-3 proven structure (16 KB B slices via global_load_lds,
// stage->sync->compute, NO pipelining -- r4/r6/r7 all regressed) with two
// changes: A fragments loaded direct from global (once/block), and grid
// y-split 8->18 so ~4 blocks/CU co-reside (VGPR=128 allows 4 waves/SIMD;
// round 3's 576-block grid was the occupancy limiter, not registers).

typedef short v8s __attribute__((ext_vector_type(8)));
typedef float v4f __attribute__((ext_vector_type(4)));

static constexpr int Sn = 9216;
static constexpr int Cn = 256;

// ws float offsets
static constexpr size_t OFF_MEAN = 0;                      // 256 floats
static constexpr size_t OFF_MROW = 256;                    // Sn uint bits (row min d)
static constexpr size_t OFF_WROW = 256 + 9216;             // Sn floats (S'_i)
static constexpr size_t OFF_VCOL = 256 + 2 * 9216;         // Sn uint bits (col min v)
static constexpr size_t OFF_SUM  = 256 + 3 * 9216;         // 1 float
static constexpr size_t OFF_IV   = 32768;                  // Sn*Cn bf16
static constexpr size_t OFF_TV   = 32768 + (size_t)Sn * Cn / 2;

__device__ __forceinline__ unsigned bf16rne(float x) {
    unsigned u = __float_as_uint(x);
    return (u + 0x7FFFu + ((u >> 16) & 1u)) >> 16;
}

__device__ __forceinline__ void gload_lds16(const void* g, void* l) {
    __builtin_amdgcn_global_load_lds(
        (const __attribute__((address_space(1))) unsigned*)g,
        (__attribute__((address_space(3))) unsigned*)l, 16, 0, 0);
}

// ---------------- init ----------------
__global__ void k_init(float* ws) {
    int t = blockIdx.x * 256 + threadIdx.x;
    if (t < Sn) {
        ((unsigned*)(ws + OFF_MROW))[t] = 0x7F800000u;  // +inf
        ws[OFF_WROW + t] = 0.0f;
        ((unsigned*)(ws + OFF_VCOL))[t] = 0x7F800000u;  // +inf
    }
    if (t == 0) ws[OFF_SUM] = 0.0f;
}

// ---------------- per-channel mean of T ----------------
__global__ void k_mean(const float* __restrict__ T, float* ws) {
    __shared__ float red[256];
    int c = blockIdx.x;
    float s = 0.f;
    for (int i = threadIdx.x; i < Sn; i += 256) s += T[(size_t)c * Sn + i];
    red[threadIdx.x] = s;
    __syncthreads();
    for (int off = 128; off > 0; off >>= 1) {
        if (threadIdx.x < off) red[threadIdx.x] += red[threadIdx.x + off];
        __syncthreads();
    }
    if (threadIdx.x == 0) ws[OFF_MEAN + c] = red[0] * (1.0f / Sn);
}

// ------- center + L2 normalize along C, emit bf16 transposed [S][C] -------
__global__ __launch_bounds__(256) void k_norm(const float* __restrict__ I,
                                              const float* __restrict__ T,
                                              float* ws) {
    __shared__ float mc[256];
    __shared__ float redI[4][64], redT[4][64];
    __shared__ float riS[64], rtS[64];
    const int tid = threadIdx.x, sl = tid & 63, cq = tid >> 6;
    const int s = blockIdx.x * 64 + sl;
    mc[tid] = ws[OFF_MEAN + tid];
    __syncthreads();
    float si = 0.f, st = 0.f;
    for (int c = cq * 64; c < cq * 64 + 64; ++c) {
        float xi = I[(size_t)c * Sn + s] - mc[c];
        float xt = T[(size_t)c * Sn + s] - mc[c];
        si += xi * xi;
        st += xt * xt;
    }
    redI[cq][sl] = si;
    redT[cq][sl] = st;
    __syncthreads();
    if (tid < 64) {
        float a = redI[0][tid] + redI[1][tid] + redI[2][tid] + redI[3][tid];
        float b = redT[0][tid] + redT[1][tid] + redT[2][tid] + redT[3][tid];
        riS[tid] = 1.0f / fmaxf(sqrtf(a), 1e-12f);
        rtS[tid] = 1.0f / fmaxf(sqrtf(b), 1e-12f);
    }
    __syncthreads();
    const float ri = riS[sl], rt = rtS[sl];
    unsigned short* Iv = (unsigned short*)(ws + OFF_IV);
    unsigned short* Tv = (unsigned short*)(ws + OFF_TV);
    uint4* Ivq = (uint4*)(Iv + (size_t)s * Cn);
    uint4* Tvq = (uint4*)(Tv + (size_t)s * Cn);
    for (int c8 = cq * 8; c8 < cq * 8 + 8; ++c8) {
        unsigned iw[4], tw[4];
#pragma unroll
        for (int h = 0; h < 4; ++h) {
            int c0 = c8 * 8 + 2 * h, c1 = c0 + 1;
            float i0 = (I[(size_t)c0 * Sn + s] - mc[c0]) * ri;
            float i1 = (I[(size_t)c1 * Sn + s] - mc[c1]) * ri;
            float t0 = (T[(size_t)c0 * Sn + s] - mc[c0]) * rt;
            float t1 = (T[(size_t)c1 * Sn + s] - mc[c1]) * rt;
            iw[h] = bf16rne(i0) | (bf16rne(i1) << 16);
            tw[h] = bf16rne(t0) | (bf16rne(t1) << 16);
        }
        Ivq[c8] = make_uint4(iw[0], iw[1], iw[2], iw[3]);
        Tvq[c8] = make_uint4(tw[0], tw[1], tw[2], tw[3]);
    }
}

// ---- round-3 proven staging: 16 KB K-slices, 8-chunk XOR swizzle ----
__device__ __forceinline__ void stage_slice(const char* Gb, char* lds,
                                            int kcs, int tid) {
    const int lane = tid & 63, wave = tid >> 6;
#pragma unroll
    for (int w = 0; w < 4; ++w) {
        int gi = wave * 4 + w;
        int row = gi * 8 + (lane >> 3);
        int p = lane & 7;
        int c = p ^ (row & 7);
        const char* g = Gb + (size_t)row * 512 + kcs * 128 + c * 16;
        gload_lds16(g, lds + gi * 1024);
    }
}

// A fragments straight from global (L2): 32 independent 16 B loads, once
// per block.  fa[mt][kk]: lane(l15,quad) holds A[row0+mt*16+l15][kk*32+quad*8..]
__device__ __forceinline__ void load_A(const v8s* __restrict__ Aq, int row0,
                                       int quad, int l15, v8s fa[4][8]) {
#pragma unroll
    for (int mt = 0; mt < 4; ++mt) {
        size_t row = row0 + mt * 16 + l15;
#pragma unroll
        for (int kk = 0; kk < 8; ++kk)
            fa[mt][kk] = Aq[row * 32 + kk * 4 + quad];
    }
}

__device__ __forceinline__ void tile_mma(const char* Bb, char* lds, int tid,
                                         const v8s fa[4][8], v4f acc[4][4]) {
    const int lane = tid & 63, wave = tid >> 6;
    const int wn = wave & 1, quad = (lane >> 4) & 3, l15 = lane & 15;
#pragma unroll
    for (int kc = 0; kc < 4; ++kc) {
        __syncthreads();
        stage_slice(Bb, lds, kc, tid);
        __syncthreads();
#pragma unroll
        for (int ks = 0; ks < 2; ++ks) {
            int c = ks * 4 + quad;
#pragma unroll
            for (int nt = 0; nt < 4; ++nt) {
                int row = wn * 64 + nt * 16 + l15;
                int p = c ^ (row & 7);
                v8s fb = *(const v8s*)(lds + row * 128 + p * 16);
#pragma unroll
                for (int mt = 0; mt < 4; ++mt)
                    acc[mt][nt] = __builtin_amdgcn_mfma_f32_16x16x32_bf16(
                        fa[mt][kc * 2 + ks], fb, acc[mt][nt], 0, 0, 0);
            }
        }
    }
}

// ---------------- pass 1: m_i = min_j d_ij ----------------
__global__ __launch_bounds__(256, 2) void k_rowmin(float* ws) {
    __shared__ __align__(16) char Bsb[16384];
    const v8s* Ivq = (const v8s*)(ws + OFF_IV);
    const char* Tvb = (const char*)(ws + OFF_TV);
    const int tid = threadIdx.x, lane = tid & 63, wave = tid >> 6;
    const int wm = wave >> 1, quad = (lane >> 4) & 3, l15 = lane & 15;
    const int i0 = blockIdx.x * 128;
    v8s fa[4][8];
    load_A(Ivq, i0 + wm * 64, quad, l15, fa);
    float mv[4][4];
#pragma unroll
    for (int mt = 0; mt < 4; ++mt)
#pragma unroll
        for (int r = 0; r < 4; ++r) mv[mt][r] = INFINITY;
    for (int t = 0; t < 4; ++t) {
        int j0 = (blockIdx.y * 4 + t) * 128;
        v4f acc[4][4];
#pragma unroll
        for (int mt = 0; mt < 4; ++mt)
#pragma unroll
            for (int nt = 0; nt < 4; ++nt)
#pragma unroll
                for (int r = 0; r < 4; ++r) acc[mt][nt][r] = 0.f;
        tile_mma(Tvb + (size_t)j0 * 512, Bsb, tid, fa, acc);
#pragma unroll
        for (int mt = 0; mt < 4; ++mt)
#pragma unroll
            for (int nt = 0; nt < 4; ++nt)
#pragma unroll
                for (int r = 0; r < 4; ++r) {
                    float d = fmaxf(0.5f - 0.5f * acc[mt][nt][r], 0.0f);
                    mv[mt][r] = fminf(mv[mt][r], d);
                }
    }
#pragma unroll
    for (int mt = 0; mt < 4; ++mt)
#pragma unroll
        for (int r = 0; r < 4; ++r) {
            float m = mv[mt][r];
            for (int off = 1; off < 16; off <<= 1)
                m = fminf(m, __shfl_xor(m, off, 64));
            if (l15 == 0)
                atomicMin((unsigned*)(ws + OFF_MROW) + i0 + wm * 64 + mt * 16 + quad * 4 + r,
                          __float_as_uint(m));
        }
}

// ---------------- pass 2: S'_i = sum_j exp(-a_i * d_ij) ----------------
__global__ __launch_bounds__(256, 2) void k_rowsum(float* ws) {
    __shared__ __align__(16) char Bsb[16384];
    const v8s* Ivq = (const v8s*)(ws + OFF_IV);
    const char* Tvb = (const char*)(ws + OFF_TV);
    const int tid = threadIdx.x, lane = tid & 63, wave = tid >> 6;
    const int wm = wave >> 1, quad = (lane >> 4) & 3, l15 = lane & 15;
    const int i0 = blockIdx.x * 128;
    v8s fa[4][8];
    load_A(Ivq, i0 + wm * 64, quad, l15, fa);
    float c1[4][4], run[4][4];
#pragma unroll
    for (int mt = 0; mt < 4; ++mt)
#pragma unroll
        for (int r = 0; r < 4; ++r) {
            int i = i0 + wm * 64 + mt * 16 + quad * 4 + r;
            float mm = __uint_as_float(((unsigned*)(ws + OFF_MROW))[i]);
            c1[mt][r] = -1.4426950408889634f * 2.0f / (mm + 1e-5f);  // -a*log2e
            run[mt][r] = 0.f;
        }
    for (int t = 0; t < 4; ++t) {
        int j0 = (blockIdx.y * 4 + t) * 128;
        v4f acc[4][4];
#pragma unroll
        for (int mt = 0; mt < 4; ++mt)
#pragma unroll
            for (int nt = 0; nt < 4; ++nt)
#pragma unroll
                for (int r = 0; r < 4; ++r) acc[mt][nt][r] = 0.f;
        tile_mma(Tvb + (size_t)j0 * 512, Bsb, tid, fa, acc);
#pragma unroll
        for (int mt = 0; mt < 4; ++mt)
#pragma unroll
            for (int nt = 0; nt < 4; ++nt)
#pragma unroll
                for (int r = 0; r < 4; ++r) {
                    float d = fmaxf(0.5f - 0.5f * acc[mt][nt][r], 0.0f);
                    run[mt][r] += __builtin_amdgcn_exp2f(c1[mt][r] * d);
                }
    }
#pragma unroll
    for (int mt = 0; mt < 4; ++mt)
#pragma unroll
        for (int r = 0; r < 4; ++r) {
            float s = run[mt][r];
            for (int off = 1; off < 16; off <<= 1)
                s += __shfl_xor(s, off, 64);
            if (l15 == 0)
                atomicAdd(ws + OFF_WROW + i0 + wm * 64 + mt * 16 + quad * 4 + r, s);
        }
}

// ------- pass 3: vcol_j = min_i [ a_i * d_ij + ln S'_i ] -------------
// Tile rows = j (A from Tv), tile cols = i (B from Iv).
__global__ __launch_bounds__(256, 2) void k_colmin(float* ws) {
    __shared__ __align__(16) char Bsb[16384];
    const char* Ivb = (const char*)(ws + OFF_IV);
    const v8s* Tvq = (const v8s*)(ws + OFF_TV);
    const int tid = threadIdx.x, lane = tid & 63, wave = tid >> 6;
    const int wm = wave >> 1, wn = wave & 1, quad = (lane >> 4) & 3, l15 = lane & 15;
    const int j0 = blockIdx.x * 128;
    v8s fa[4][8];
    load_A(Tvq, j0 + wm * 64, quad, l15, fa);
    float vmin[4][4];
#pragma unroll
    for (int mt = 0; mt < 4; ++mt)
#pragma unroll
        for (int r = 0; r < 4; ++r) vmin[mt][r] = INFINITY;
    for (int t = 0; t < 4; ++t) {
        int ib = (blockIdx.y * 4 + t) * 128;
        v4f acc[4][4];
#pragma unroll
        for (int mt = 0; mt < 4; ++mt)
#pragma unroll
            for (int nt = 0; nt < 4; ++nt)
#pragma unroll
                for (int r = 0; r < 4; ++r) acc[mt][nt][r] = 0.f;
        tile_mma(Ivb + (size_t)ib * 512, Bsb, tid, fa, acc);  // acc = cos[j][i]
#pragma unroll
        for (int nt = 0; nt < 4; ++nt) {
            int i = ib + wn * 64 + nt * 16 + l15;
            float mm = __uint_as_float(((unsigned*)(ws + OFF_MROW))[i]);
            float a = 2.0f / (mm + 1e-5f);
            float lw = __builtin_amdgcn_logf(ws[OFF_WROW + i]) * 0.6931471805599453f;
#pragma unroll
            for (int mt = 0; mt < 4; ++mt)
#pragma unroll
                for (int r = 0; r < 4; ++r) {
                    float d = fmaxf(0.5f - 0.5f * acc[mt][nt][r], 0.0f);
                    vmin[mt][r] = fminf(vmin[mt][r], a * d + lw);
                }
        }
    }
#pragma unroll
    for (int mt = 0; mt < 4; ++mt)
#pragma unroll
        for (int r = 0; r < 4; ++r) {
            float v = vmin[mt][r];
            for (int off = 1; off < 16; off <<= 1)
                v = fminf(v, __shfl_xor(v, off, 64));
            if (l15 == 0)
                atomicMin((unsigned*)(ws + OFF_VCOL) + j0 + wm * 64 + mt * 16 + quad * 4 + r,
                          __float_as_uint(v));
        }
}

// ---------------- final: parallel sum then scalar write ----------------
__global__ void k_fsum(float* ws) {
    __shared__ float red[256];
    int j0 = blockIdx.x * 256 + threadIdx.x;
    float s = expf(-__uint_as_float(((const unsigned*)(ws + OFF_VCOL))[j0]));
    red[threadIdx.x] = s;
    __syncthreads();
    for (int off = 128; off > 0; off >>= 1) {
        if (threadIdx.x < off) red[threadIdx.x] += red[threadIdx.x + off];
        __syncthreads();
    }
    if (threadIdx.x == 0) atomicAdd(ws + OFF_SUM, red[0]);
}

__global__ void k_fwrite(const float* __restrict__ ws, float* __restrict__ out) {
    out[0] = logf((float)Sn) - logf(ws[OFF_SUM]);
}

extern "C" void kernel_launch(void* const* d_in, const int* in_sizes, int n_in,
                              void* d_out, int out_size, void* d_ws, size_t ws_size,
                              hipStream_t stream) {
    const float* I = (const float*)d_in[0];
    const float* T = (const float*)d_in[1];
    float* ws = (float*)d_ws;
    float* out = (float*)d_out;

    k_init<<<36, 256, 0, stream>>>(ws);
    k_mean<<<Cn, 256, 0, stream>>>(T, ws);
    k_norm<<<144, 256, 0, stream>>>(I, T, ws);
    k_rowmin<<<dim3(72, 18), 256, 0, stream>>>(ws);
    k_rowsum<<<dim3(72, 18), 256, 0, stream>>>(ws);
    k_colmin<<<dim3(72, 18), 256, 0, stream>>>(ws);
    k_fsum<<<36, 256, 0, stream>>>(ws);
    k_fwrite<<<1, 1, 0, stream>>>(ws, out);
}